// Round 5
// baseline (238.978 us; speedup 1.0000x reference)
//
#include <hip/hip_runtime.h>
#include <stdint.h>

#define K_DIM 8192
#define N_DIM 28672

typedef _Float16 half8 __attribute__((ext_vector_type(8)));
typedef _Float16 half2t __attribute__((ext_vector_type(2)));
typedef float f32x16 __attribute__((ext_vector_type(16)));

// ---- prep: x f32 [32][8192] -> xp f16 [K/8][32][8] in A-fragment slot order
__global__ __launch_bounds__(256) void prep_x(const float* __restrict__ x,
                                              _Float16* __restrict__ xp) {
  int idx = blockIdx.x * 256 + threadIdx.x;  // 32768 = 1024 word-rows * 32 m
  int m  = idx & 31;
  int k8 = idx >> 5;
  const float* p = x + (size_t)m * K_DIM + (size_t)k8 * 8;
  float4 xa = *(const float4*)p;
  float4 xb = *(const float4*)(p + 4);
  half2t p0 = __builtin_bit_cast(half2t, __builtin_amdgcn_cvt_pkrtz(xa.x, xb.x));
  half2t p1 = __builtin_bit_cast(half2t, __builtin_amdgcn_cvt_pkrtz(xa.y, xb.y));
  half2t p2 = __builtin_bit_cast(half2t, __builtin_amdgcn_cvt_pkrtz(xa.z, xb.z));
  half2t p3 = __builtin_bit_cast(half2t, __builtin_amdgcn_cvt_pkrtz(xa.w, xb.w));
  half8 o;
  o[0] = p0[0]; o[1] = p0[1]; o[2] = p1[0]; o[3] = p1[1];
  o[4] = p2[0]; o[5] = p2[1]; o[6] = p3[0]; o[7] = p3[1];
  *(half8*)(xp + ((size_t)k8 * 32 + m) * 8) = o;
}

// out[m][n] = bias[n]  (split-K atomics accumulate on top)
__global__ __launch_bounds__(256) void init_out(const float* __restrict__ bias,
                                                float* __restrict__ out) {
  int idx = blockIdx.x * 256 + threadIdx.x;   // 917504 total
  int n = idx % N_DIM;
  out[idx] = bias[n];
}

// int4 word -> 8 f16 slots [n0,n4,n1,n5,n2,n6,n3,n7], value (n-8)*s (exact add)
static __device__ __forceinline__ half8 dqs(uint32_t w, half2t sh) {
  const uint32_t M4 = 0x000F000Fu, E = 0x64006400u;
  half2t off; off[0] = (_Float16)(-1032.0f); off[1] = (_Float16)(-1032.0f);
  half2t v0 = (__builtin_bit_cast(half2t, ( w        & M4) | E) + off) * sh;
  half2t v1 = (__builtin_bit_cast(half2t, ((w >> 4)  & M4) | E) + off) * sh;
  half2t v2 = (__builtin_bit_cast(half2t, ((w >> 8)  & M4) | E) + off) * sh;
  half2t v3 = (__builtin_bit_cast(half2t, ((w >> 12) & M4) | E) + off) * sh;
  half8 r;
  r[0] = v0[0]; r[1] = v0[1]; r[2] = v1[0]; r[3] = v1[1];
  r[4] = v2[0]; r[5] = v2[1]; r[6] = v3[0]; r[7] = v3[1];
  return r;
}

static __device__ __forceinline__ void gl_lds16(const void* g, void* l) {
  __builtin_amdgcn_global_load_lds(
      (const __attribute__((address_space(1))) uint32_t*)g,
      (__attribute__((address_space(3))) uint32_t*)l, 16, 0, 0);
}

// Wave = 32 cols x 256 k; block = 4 waves sharing a 16KB A-slice in LDS.
// Grid = 224 col-tiles x 32 k-slices; split-K via f32 HW atomics.
// ONE barrier per kernel; waves fully independent afterwards.
__global__ __launch_bounds__(256, 8) void qgemm(
    const uint32_t* __restrict__ q, const float* __restrict__ scales,
    const _Float16* __restrict__ xp, float* __restrict__ out) {
  __shared__ __attribute__((aligned(16))) char Abuf[16384];
  const int tid  = threadIdx.x;
  const int w    = tid >> 6;
  const int lane = tid & 63;
  const int h    = lane >> 5;
  const int nl   = lane & 31;
  const int bid  = blockIdx.x;
  const int ks   = bid & 31;            // k-slice (256 k each)
  const int col0 = (bid >> 5) << 7;     // 128-col tile
  const int colw = col0 + (w << 5);     // wave's 32 cols
  const int kr0  = ks << 5;             // first word-row (32 rows)

  // scale loads (drained by the sync below; values wanted before compute)
  float s0f = scales[(size_t)(ks * 2)     * N_DIM + colw + nl];
  float s1f = scales[(size_t)(ks * 2 + 1) * N_DIM + colw + nl];

  // stage A-slice: 16KB contiguous from xp (exact fragment order), 4 DMA/wave
  {
    const char* src = (const char*)xp + (size_t)kr0 * 512 + w * 4096 + (size_t)lane * 16;
    char* dst = Abuf + w * 4096;
#pragma unroll
    for (int j = 0; j < 4; j++) gl_lds16(src + j * 1024, dst + j * 1024);
  }

  // burst ALL q loads for this wave (16 insts, 2 rows each) before the sync
  uint32_t wq[16];
  const uint32_t* qp = q + (size_t)(kr0 + h) * N_DIM + colw + nl;
#pragma unroll
  for (int i = 0; i < 16; i++) wq[i] = qp[(size_t)(2 * i) * N_DIM];

  __syncthreads();   // vmcnt(0)+barrier: A visible; q/scales ready in VGPRs too

  half2t sh0 = __builtin_bit_cast(half2t, __builtin_amdgcn_cvt_pkrtz(s0f, s0f));
  half2t sh1 = __builtin_bit_cast(half2t, __builtin_amdgcn_cvt_pkrtz(s1f, s1f));

  f32x16 acc;
#pragma unroll
  for (int j = 0; j < 16; j++) acc[j] = 0.0f;

#pragma unroll
  for (int i = 0; i < 16; i++) {
    // A row-in-slice r = 2i + h, fragment at ((r*32)+nl)*16
    half8 af = *(const half8*)(Abuf + (size_t)(((2 * i + h) * 32) + nl) * 16);
    acc = __builtin_amdgcn_mfma_f32_32x32x16_f16(af, dqs(wq[i], i < 8 ? sh0 : sh1),
                                                 acc, 0, 0, 0);
  }

  // C/D layout (32x32): col = lane&31, row = (reg&3) + 8*(reg>>2) + 4*(lane>>5)
#pragma unroll
  for (int j = 0; j < 16; j++) {
    int row = (j & 3) + ((j >> 2) << 3) + (h << 2);
    unsafeAtomicAdd(&out[(size_t)row * N_DIM + colw + nl], acc[j]);
  }
}

extern "C" void kernel_launch(void* const* d_in, const int* in_sizes, int n_in,
                              void* d_out, int out_size, void* d_ws, size_t ws_size,
                              hipStream_t stream) {
  const float*    xf      = (const float*)d_in[0];
  const uint32_t* qweight = (const uint32_t*)d_in[1];
  const float*    scales  = (const float*)d_in[2];
  const float*    bias    = (const float*)d_in[3];
  float*          out     = (float*)d_out;
  _Float16*       xp      = (_Float16*)d_ws;   // 512 KB scratch

  init_out<<<dim3(3584), dim3(256), 0, stream>>>(bias, out);
  prep_x<<<dim3(128), dim3(256), 0, stream>>>(xf, xp);
  qgemm<<<dim3(224 * 32), dim3(256), 0, stream>>>(qweight, scales, xp, out);
}

// Round 6
// 209.779 us; speedup vs baseline: 1.1392x; 1.1392x over previous
//
#include <hip/hip_runtime.h>
#include <stdint.h>

#define K_DIM 8192
#define N_DIM 28672

typedef _Float16 half8 __attribute__((ext_vector_type(8)));
typedef _Float16 half2t __attribute__((ext_vector_type(2)));
typedef float f32x16 __attribute__((ext_vector_type(16)));

// ---- prep: x f32 [32][8192] -> xp f16 [K/8][32][8] in A-fragment slot order
__global__ __launch_bounds__(256) void prep_x(const float* __restrict__ x,
                                              _Float16* __restrict__ xp) {
  int idx = blockIdx.x * 256 + threadIdx.x;  // 32768 = 1024 word-rows * 32 m
  int m  = idx & 31;
  int k8 = idx >> 5;
  const float* p = x + (size_t)m * K_DIM + (size_t)k8 * 8;
  float4 xa = *(const float4*)p;
  float4 xb = *(const float4*)(p + 4);
  half2t p0 = __builtin_bit_cast(half2t, __builtin_amdgcn_cvt_pkrtz(xa.x, xb.x));
  half2t p1 = __builtin_bit_cast(half2t, __builtin_amdgcn_cvt_pkrtz(xa.y, xb.y));
  half2t p2 = __builtin_bit_cast(half2t, __builtin_amdgcn_cvt_pkrtz(xa.z, xb.z));
  half2t p3 = __builtin_bit_cast(half2t, __builtin_amdgcn_cvt_pkrtz(xa.w, xb.w));
  half8 o;
  o[0] = p0[0]; o[1] = p0[1]; o[2] = p1[0]; o[3] = p1[1];
  o[4] = p2[0]; o[5] = p2[1]; o[6] = p3[0]; o[7] = p3[1];
  *(half8*)(xp + ((size_t)k8 * 32 + m) * 8) = o;
}

// int4 word -> 8 f16 slots [n0,n4,n1,n5,n2,n6,n3,n7], value (n-8)*s (exact add)
static __device__ __forceinline__ half8 dqs(uint32_t w, half2t sh) {
  const uint32_t M4 = 0x000F000Fu, E = 0x64006400u;
  half2t off; off[0] = (_Float16)(-1032.0f); off[1] = (_Float16)(-1032.0f);
  half2t v0 = (__builtin_bit_cast(half2t, ( w        & M4) | E) + off) * sh;
  half2t v1 = (__builtin_bit_cast(half2t, ((w >> 4)  & M4) | E) + off) * sh;
  half2t v2 = (__builtin_bit_cast(half2t, ((w >> 8)  & M4) | E) + off) * sh;
  half2t v3 = (__builtin_bit_cast(half2t, ((w >> 12) & M4) | E) + off) * sh;
  half8 r;
  r[0] = v0[0]; r[1] = v0[1]; r[2] = v1[0]; r[3] = v1[1];
  r[4] = v2[0]; r[5] = v2[1]; r[6] = v3[0]; r[7] = v3[1];
  return r;
}

// Block = 4 waves x 32 cols; in-block split-K x4 (each wave K/4 = 16 groups).
// Register-pipelined: q depth-2, A depth-1, FIFO-safe issue order
// (A(g+1), s(g+1), then q(g+2)) so no A-wait ever drains the q prefetch.
// No atomics, no mid-loop barriers; one __syncthreads before the LDS reduce.
__global__ __launch_bounds__(256, 4) void qgemm(
    const uint32_t* __restrict__ q, const float* __restrict__ scales,
    const float* __restrict__ bias, const _Float16* __restrict__ xp,
    float* __restrict__ out) {
  __shared__ float red[4][32][32];   // 16 KB
  const int tid  = threadIdx.x;
  const int w    = tid >> 6;
  const int lane = tid & 63;
  const int h    = lane >> 5;
  const int nl   = lane & 31;
  const int col0 = blockIdx.x << 5;
  const int wr0  = w << 8;           // 256 word-rows per wave (K/4)

  const uint32_t* qp = q + (size_t)(wr0 + h) * N_DIM + col0 + nl;
  const half8*    ap = (const half8*)xp + (size_t)(wr0 + h) * 32 + nl;
  const float*    sp = scales + (size_t)(w << 4) * N_DIM + col0 + nl;

  uint32_t qb[3][8];
  half8    ab[2][8];
  float    sb[2];

  auto loadQ = [&](int g, uint32_t (&dst)[8]) {
#pragma unroll
    for (int i = 0; i < 8; i++)
      dst[i] = qp[(size_t)(16 * g + 2 * i) * N_DIM];
  };
  auto loadA = [&](int g, half8 (&dst)[8]) {
#pragma unroll
    for (int i = 0; i < 8; i++)
      dst[i] = ap[(size_t)(16 * g + 2 * i) * 32];
  };

  f32x16 acc;
#pragma unroll
  for (int j = 0; j < 16; j++) acc[j] = 0.0f;

  // prologue — FIFO: q(0), A(0), s(0), q(1)
  loadQ(0, qb[0]);
  loadA(0, ab[0]);
  sb[0] = sp[0];
  loadQ(1, qb[1]);

#pragma unroll
  for (int g = 0; g < 16; g++) {
    if (g + 1 < 16) {                       // A depth-1 (L2-resident xp)
      loadA(g + 1, ab[(g + 1) & 1]);
      sb[(g + 1) & 1] = sp[(size_t)(g + 1) * N_DIM];
    }
    if (g + 2 < 16) loadQ(g + 2, qb[(g + 2) % 3]);   // q depth-2 (HBM)
    float s = sb[g & 1];
    half2t sh = __builtin_bit_cast(half2t, __builtin_amdgcn_cvt_pkrtz(s, s));
#pragma unroll
    for (int i = 0; i < 8; i++)
      acc = __builtin_amdgcn_mfma_f32_32x32x16_f16(
          ab[g & 1][i], dqs(qb[g % 3][i], sh), acc, 0, 0, 0);
  }

  // C/D layout (32x32): col = lane&31, row = (reg&3) + 8*(reg>>2) + 4*(lane>>5)
#pragma unroll
  for (int j = 0; j < 16; j++) {
    int row = (j & 3) + ((j >> 2) << 3) + (h << 2);
    red[w][row][nl] = acc[j];
  }
  __syncthreads();

  const int col = tid & 31;
  const int r0  = tid >> 5;   // 0..7
  float bz = bias[col0 + col];
#pragma unroll
  for (int i = 0; i < 4; i++) {
    int row = r0 + (i << 3);
    float v = red[0][row][col] + red[1][row][col] +
              red[2][row][col] + red[3][row][col];
    out[(size_t)row * N_DIM + col0 + col] = v + bz;
  }
}

extern "C" void kernel_launch(void* const* d_in, const int* in_sizes, int n_in,
                              void* d_out, int out_size, void* d_ws, size_t ws_size,
                              hipStream_t stream) {
  const float*    xf      = (const float*)d_in[0];
  const uint32_t* qweight = (const uint32_t*)d_in[1];
  const float*    scales  = (const float*)d_in[2];
  const float*    bias    = (const float*)d_in[3];
  float*          out     = (float*)d_out;
  _Float16*       xp      = (_Float16*)d_ws;   // 512 KB scratch

  prep_x<<<dim3(128), dim3(256), 0, stream>>>(xf, xp);
  qgemm<<<dim3(N_DIM / 32), dim3(256), 0, stream>>>(qweight, scales, bias, xp, out);
}

// Round 7
// 208.906 us; speedup vs baseline: 1.1440x; 1.0042x over previous
//
#include <hip/hip_runtime.h>
#include <stdint.h>

#define K_DIM 8192
#define N_DIM 28672

typedef _Float16 half8 __attribute__((ext_vector_type(8)));
typedef _Float16 half2t __attribute__((ext_vector_type(2)));
typedef float f32x16 __attribute__((ext_vector_type(16)));

// ---- prep: x f32 [32][8192] -> xp f16 [K/8][32][8] in A-fragment slot order
__global__ __launch_bounds__(256) void prep_x(const float* __restrict__ x,
                                              _Float16* __restrict__ xp) {
  int idx = blockIdx.x * 256 + threadIdx.x;  // 32768 = 1024 word-rows * 32 m
  int m  = idx & 31;
  int k8 = idx >> 5;
  const float* p = x + (size_t)m * K_DIM + (size_t)k8 * 8;
  float4 xa = *(const float4*)p;
  float4 xb = *(const float4*)(p + 4);
  half2t p0 = __builtin_bit_cast(half2t, __builtin_amdgcn_cvt_pkrtz(xa.x, xb.x));
  half2t p1 = __builtin_bit_cast(half2t, __builtin_amdgcn_cvt_pkrtz(xa.y, xb.y));
  half2t p2 = __builtin_bit_cast(half2t, __builtin_amdgcn_cvt_pkrtz(xa.z, xb.z));
  half2t p3 = __builtin_bit_cast(half2t, __builtin_amdgcn_cvt_pkrtz(xa.w, xb.w));
  half8 o;
  o[0] = p0[0]; o[1] = p0[1]; o[2] = p1[0]; o[3] = p1[1];
  o[4] = p2[0]; o[5] = p2[1]; o[6] = p3[0]; o[7] = p3[1];
  *(half8*)(xp + ((size_t)k8 * 32 + m) * 8) = o;
}

// int4 word -> 8 f16 slots [n0,n4,n1,n5,n2,n6,n3,n7], value (n-8)*s (exact add)
static __device__ __forceinline__ half8 dqs(uint32_t w, half2t sh) {
  const uint32_t M4 = 0x000F000Fu, E = 0x64006400u;
  half2t off; off[0] = (_Float16)(-1032.0f); off[1] = (_Float16)(-1032.0f);
  half2t v0 = (__builtin_bit_cast(half2t, ( w        & M4) | E) + off) * sh;
  half2t v1 = (__builtin_bit_cast(half2t, ((w >> 4)  & M4) | E) + off) * sh;
  half2t v2 = (__builtin_bit_cast(half2t, ((w >> 8)  & M4) | E) + off) * sh;
  half2t v3 = (__builtin_bit_cast(half2t, ((w >> 12) & M4) | E) + off) * sh;
  half8 r;
  r[0] = v0[0]; r[1] = v0[1]; r[2] = v1[0]; r[3] = v1[1];
  r[4] = v2[0]; r[5] = v2[1]; r[6] = v3[0]; r[7] = v3[1];
  return r;
}

// Block = 1024 thr = 16 waves, all on the SAME 32 cols; in-block split-K x16
// (each wave 512 k = 4 groups, 32 MFMAs). No atomics, no register pipeline —
// aggregate MLP comes from 32 resident waves/CU (launch_bounds caps VGPR=64).
// One barrier; 16-way LDS reduce + bias in the epilogue.
__global__ __launch_bounds__(1024, 8) void qgemm(
    const uint32_t* __restrict__ q, const float* __restrict__ scales,
    const float* __restrict__ bias, const _Float16* __restrict__ xp,
    float* __restrict__ out) {
  __shared__ float red[16][32][32];   // 64 KB
  const int tid  = threadIdx.x;
  const int w    = tid >> 6;          // 0..15
  const int lane = tid & 63;
  const int h    = lane >> 5;
  const int nl   = lane & 31;
  const int col0 = blockIdx.x << 5;
  const int wr0  = w << 6;            // 64 word-rows per wave (512 k)

  const uint32_t* qp = q + (size_t)(wr0 + h) * N_DIM + col0 + nl;
  const half8*    ap = (const half8*)xp + (size_t)(wr0 + h) * 32 + nl;
  const float*    sp = scales + (size_t)(w << 2) * N_DIM + col0 + nl;

  // 4 group scales up-front (simple, compiler hoists the loads early)
  float s4[4];
#pragma unroll
  for (int g = 0; g < 4; g++) s4[g] = sp[(size_t)g * N_DIM];

  f32x16 acc;
#pragma unroll
  for (int j = 0; j < 16; j++) acc[j] = 0.0f;

#pragma unroll
  for (int g = 0; g < 4; g++) {
    half2t sh = __builtin_bit_cast(half2t, __builtin_amdgcn_cvt_pkrtz(s4[g], s4[g]));
#pragma unroll
    for (int i = 0; i < 8; i++) {
      int r = 16 * g + 2 * i;
      half8 af = ap[(size_t)r * 32];
      acc = __builtin_amdgcn_mfma_f32_32x32x16_f16(af, dqs(qp[(size_t)r * N_DIM], sh),
                                                   acc, 0, 0, 0);
    }
  }

  // C/D layout (32x32): col = lane&31, row = (reg&3) + 8*(reg>>2) + 4*(lane>>5)
#pragma unroll
  for (int j = 0; j < 16; j++) {
    int row = (j & 3) + ((j >> 2) << 3) + (h << 2);
    red[w][row][nl] = acc[j];   // 2-way bank alias only (free)
  }
  __syncthreads();

  // 1024 threads == 1024 output elements of this 32x32 tile
  const int row = tid >> 5;
  const int col = tid & 31;
  float v = bias[col0 + col];
#pragma unroll
  for (int i = 0; i < 16; i++) v += red[i][row][col];
  out[(size_t)row * N_DIM + col0 + col] = v;
}

extern "C" void kernel_launch(void* const* d_in, const int* in_sizes, int n_in,
                              void* d_out, int out_size, void* d_ws, size_t ws_size,
                              hipStream_t stream) {
  const float*    xf      = (const float*)d_in[0];
  const uint32_t* qweight = (const uint32_t*)d_in[1];
  const float*    scales  = (const float*)d_in[2];
  const float*    bias    = (const float*)d_in[3];
  float*          out     = (float*)d_out;
  _Float16*       xp      = (_Float16*)d_ws;   // 512 KB scratch

  prep_x<<<dim3(128), dim3(256), 0, stream>>>(xf, xp);
  qgemm<<<dim3(N_DIM / 32), dim3(1024), 0, stream>>>(qweight, scales, bias, xp, out);
}